// Round 3
// baseline (117.947 us; speedup 1.0000x reference)
//
#include <hip/hip_runtime.h>
#include <math.h>

#define NPTS 262144
#define BATCH 32

// ---------- wave (64-lane) reductions ----------
__device__ __forceinline__ float wred_sum(float v) {
#pragma unroll
    for (int o = 32; o; o >>= 1) v += __shfl_down(v, o);
    return v;
}
__device__ __forceinline__ unsigned wred_usum(unsigned v) {
#pragma unroll
    for (int o = 32; o; o >>= 1) v += __shfl_down(v, o);
    return v;
}
__device__ __forceinline__ float wred_min(float v) {
#pragma unroll
    for (int o = 32; o; o >>= 1) v = fminf(v, __shfl_down(v, o));
    return v;
}
__device__ __forceinline__ float wred_max(float v) {
#pragma unroll
    for (int o = 32; o; o >>= 1) v = fmaxf(v, __shfl_down(v, o));
    return v;
}

// Partial layout in d_ws:
//   float pf[27][nblk] : 0..4 S[c], 5..9 T[c], 10 lse_sum,
//                        11..14 gt z-sum (cls1..4), 15..18 pred z-sum,
//                        19..26 {mn2x,mx2x,mn2y,mx2y,mn3x,mx3x,mn3y,mx3y}
//   uint  pi[9][nblk]  : 0..4 bincount (also = per-batch GT counts), 5..8 pred cnt
// Stage-2: float s2[16 + 24*BATCH]
//   s2[0..10] global S,T,lse; s2[11..15] dist (bincount, exact in f32)
//   s2[16 + b*24 + f], f: 0..3 gtz, 4..7 prz, 8..15 minmax, 16..19 gtc, 20..23 prc

template<int ITERS>
__global__ __launch_bounds__(256) void bsl_main(
    const float* __restrict__ outputs, const int* __restrict__ labels,
    const float* __restrict__ points, float* __restrict__ pf,
    unsigned int* __restrict__ pi, int bpb, unsigned int* __restrict__ counter)
{
    const int blk = blockIdx.x;
    const int nblk = gridDim.x;
    const int b = blk / bpb;
    const int seg = blk % bpb;
    const int seg_start = seg * (ITERS * 1024);
    const int tid = threadIdx.x;

    if (blk == 0 && tid == 0) *counter = 0u;  // reset for bsl_reduce (stream-ordered)

    float S[5] = {0, 0, 0, 0, 0};
    float T[5] = {0, 0, 0, 0, 0};
    float lseacc = 0.f;
    float gtz[4] = {0, 0, 0, 0};
    float prz[4] = {0, 0, 0, 0};
    const float INF = __int_as_float(0x7f800000);
    float mn2x = INF, mx2x = -INF, mn2y = INF, mx2y = -INF;
    float mn3x = INF, mx3x = -INF, mn3y = INF, mx3y = -INF;
    unsigned bc[5] = {0, 0, 0, 0, 0}, prc[4] = {0, 0, 0, 0};

    const float* obase = outputs + (size_t)b * 5 * NPTS;
    const int*   lbase = labels + (size_t)b * NPTS;
    const float* pbase = points + (size_t)b * NPTS * 3;

#pragma unroll
    for (int it = 0; it < ITERS; ++it) {
        const int n = seg_start + it * 1024 + tid * 4;
        float4 L[5];
#pragma unroll
        for (int c = 0; c < 5; ++c)
            L[c] = *(const float4*)(obase + (size_t)c * NPTS + n);
        const int4 lab = *(const int4*)(lbase + n);
        const float4* pp = (const float4*)(pbase + (size_t)n * 3);
        const float4 p0 = pp[0], p1 = pp[1], p2 = pp[2];
        const float xs[4] = {p0.x, p0.w, p1.z, p2.y};
        const float ys[4] = {p0.y, p1.x, p1.w, p2.z};
        const float zs[4] = {p0.z, p1.y, p2.x, p2.w};
        const int   lb[4] = {lab.x, lab.y, lab.z, lab.w};
#pragma unroll
        for (int j = 0; j < 4; ++j) {
            float v[5];
#pragma unroll
            for (int c = 0; c < 5; ++c) v[c] = ((const float*)&L[c])[j];
            // first-max argmax (JAX tie-break semantics)
            float best = v[0]; int pred = 0;
#pragma unroll
            for (int c = 1; c < 5; ++c)
                if (v[c] > best) { best = v[c]; pred = c; }
            float e = 0.f;
#pragma unroll
            for (int c = 0; c < 5; ++c) e += __expf(v[c] - best);
            const float lse = best + __logf(e);
            lseacc += lse;
            const int y = lb[j];
#pragma unroll
            for (int c = 0; c < 5; ++c) {
                S[c] += v[c];
                const bool is = (y == c);
                T[c] += is ? (lse - v[c]) : 0.f;
                bc[c] += is ? 1u : 0u;
            }
            const float z = zs[j];
#pragma unroll
            for (int k = 0; k < 4; ++k) {
                const bool gy = (y == k + 1), py = (pred == k + 1);
                gtz[k] += gy ? z : 0.f;
                prz[k] += py ? z : 0.f;
                prc[k] += py ? 1u : 0u;
            }
            const float x = xs[j], yv = ys[j];
            // reference: mp = points*mask -> zeros included in min/max
            const float a2x = (pred == 2) ? x : 0.f;
            const float a2y = (pred == 2) ? yv : 0.f;
            const float a3x = (pred == 3) ? x : 0.f;
            const float a3y = (pred == 3) ? yv : 0.f;
            mn2x = fminf(mn2x, a2x); mx2x = fmaxf(mx2x, a2x);
            mn2y = fminf(mn2y, a2y); mx2y = fmaxf(mx2y, a2y);
            mn3x = fminf(mn3x, a3x); mx3x = fmaxf(mx3x, a3x);
            mn3y = fminf(mn3y, a3y); mx3y = fmaxf(mx3y, a3y);
        }
    }

    float fv[27] = {S[0], S[1], S[2], S[3], S[4],
                    T[0], T[1], T[2], T[3], T[4],
                    lseacc,
                    gtz[0], gtz[1], gtz[2], gtz[3],
                    prz[0], prz[1], prz[2], prz[3],
                    mn2x, mx2x, mn2y, mx2y, mn3x, mx3x, mn3y, mx3y};
    unsigned iv[9] = {bc[0], bc[1], bc[2], bc[3], bc[4],
                      prc[0], prc[1], prc[2], prc[3]};

    __shared__ float sf[4][27];
    __shared__ unsigned si[4][9];
    const int wid = tid >> 6, lane = tid & 63;
#pragma unroll
    for (int vdx = 0; vdx < 27; ++vdx) {
        float r;
        if (vdx < 19) r = wred_sum(fv[vdx]);
        else if (((vdx - 19) & 1) == 0) r = wred_min(fv[vdx]);
        else r = wred_max(fv[vdx]);
        if (lane == 0) sf[wid][vdx] = r;
    }
#pragma unroll
    for (int vdx = 0; vdx < 9; ++vdx) {
        unsigned r = wred_usum(iv[vdx]);
        if (lane == 0) si[wid][vdx] = r;
    }
    __syncthreads();
    if (tid == 0) {
#pragma unroll
        for (int vdx = 0; vdx < 27; ++vdx) {
            float r;
            if (vdx < 19) r = sf[0][vdx] + sf[1][vdx] + sf[2][vdx] + sf[3][vdx];
            else if (((vdx - 19) & 1) == 0)
                r = fminf(fminf(sf[0][vdx], sf[1][vdx]), fminf(sf[2][vdx], sf[3][vdx]));
            else
                r = fmaxf(fmaxf(sf[0][vdx], sf[1][vdx]), fmaxf(sf[2][vdx], sf[3][vdx]));
            pf[(size_t)vdx * nblk + blk] = r;
        }
#pragma unroll
        for (int vdx = 0; vdx < 9; ++vdx)
            pi[(size_t)vdx * nblk + blk] = si[0][vdx] + si[1][vdx] + si[2][vdx] + si[3][vdx];
    }
}

// One task per block (784 blocks, concurrent). Last-done block runs the
// tiny finalize (saves a kernel launch / graph-node gap).
__global__ __launch_bounds__(64) void bsl_reduce(
    const float* __restrict__ pf, const unsigned int* __restrict__ pi,
    int bpb, float* __restrict__ s2, unsigned int* __restrict__ counter,
    float* __restrict__ out)
{
    const int nblk = BATCH * bpb;
    const int t = blockIdx.x;
    const int lane = threadIdx.x;
    const float INF = __int_as_float(0x7f800000);
    __shared__ int isLast;
    __shared__ float sm[16 + 24 * BATCH];

    if (t < 11) {
        const float4* p4 = (const float4*)(pf + (size_t)t * nblk);
        const int n4 = nblk >> 2;
        float s = 0.f;
#pragma unroll 8
        for (int i = lane; i < n4; i += 64) {
            const float4 v = p4[i];
            s += (v.x + v.y) + (v.z + v.w);
        }
        s = wred_sum(s);
        if (lane == 0) s2[t] = s;
    } else if (t < 16) {
        const int v = t - 11;
        const uint4* p4 = (const uint4*)(pi + (size_t)v * nblk);
        const int n4 = nblk >> 2;
        unsigned s = 0;
#pragma unroll 8
        for (int i = lane; i < n4; i += 64) {
            const uint4 u = p4[i];
            s += u.x + u.y + u.z + u.w;
        }
        s = wred_usum(s);
        if (lane == 0) s2[t] = (float)s;   // exact: <= 2^23
    } else {
        const int u = t - 16;
        const int b = u / 24;
        const int f = u % 24;
        const int base = b * bpb;
        if (f < 8) {
            float s = 0.f;
            for (int i = lane; i < bpb; i += 64) s += pf[(size_t)(11 + f) * nblk + base + i];
            s = wred_sum(s);
            if (lane == 0) s2[t] = s;
        } else if (f < 16) {
            const int g = f - 8;
            const bool ismin = ((g & 1) == 0);
            float s = ismin ? INF : -INF;
            for (int i = lane; i < bpb; i += 64) {
                const float x = pf[(size_t)(19 + g) * nblk + base + i];
                s = ismin ? fminf(s, x) : fmaxf(s, x);
            }
            s = ismin ? wred_min(s) : wred_max(s);
            if (lane == 0) s2[t] = s;
        } else {
            const int g = f - 16;
            // g<4: per-batch GT count == per-batch bincount rows 1..4
            const int row = (g < 4) ? (1 + g) : (5 + (g - 4));
            unsigned s = 0;
            for (int i = lane; i < bpb; i += 64) s += pi[(size_t)row * nblk + base + i];
            s = wred_usum(s);
            if (lane == 0) s2[t] = (float)s;  // exact: <= 262144
        }
    }

    // ---- last-block-done finalize ----
    if (lane == 0) {
        __threadfence();                       // release s2[t]
        const unsigned old = atomicAdd(counter, 1u);
        isLast = (old == (unsigned)(gridDim.x - 1)) ? 1 : 0;
    }
    __syncthreads();
    if (!isLast) return;
    __threadfence();                           // acquire all s2 writes

    for (int i = lane; i < 16 + 24 * BATCH; i += 64) sm[i] = s2[i];
    __syncthreads();

    const float BASE_W[5] = {0.8f, 2.0f, 1.5f, 1.5f, 3.5f};
    const int pc[12]  = {1, 1, 1, 2, 2, 2, 3, 3, 3, 4, 4, 4};
    const int prf[12] = {2, 3, 4, 1, 3, 4, 1, 2, 4, 1, 2, 3};
    const float ps[12] = {-1.f, -1.f, -1.f, 1.f, -1.f, -1.f, 1.f, 1.f, -1.f, 1.f, 1.f, 1.f};

    // lane b (< BATCH) computes batch b's clipped weights; others contribute 0
    float w[5] = {0, 0, 0, 0, 0};
    if (lane < BATCH) {
        const float* R = sm + 16 + lane * 24;
        for (int c = 0; c < 5; ++c) w[c] = BASE_W[c];
        float gtm[4], prm[4];
        bool gv[4], pv[4];
#pragma unroll
        for (int k = 0; k < 4; ++k) {
            const float c1 = R[16 + k];
            gv[k] = (c1 > 0.f);
            gtm[k] = R[k] / fmaxf(c1, 1.f);
            const float c2 = R[20 + k];
            pv[k] = (c2 > 0.f);
            prm[k] = R[4 + k] / fmaxf(c2, 1.f);
        }
#pragma unroll
        for (int p = 0; p < 12; ++p) {
            const int cid = pc[p], ref = prf[p];
            float add = 0.f;
            if (pv[cid - 1] && gv[ref - 1]) {
                const float diff = ps[p] * (prm[cid - 1] - gtm[ref - 1]);
                add = 50.f / (1.f + expf(10.f * diff));  // ALPHA*sigmoid(-10*diff)
            }
            w[cid] += add;
            w[ref] += 0.3f * add;
        }
        const float mn2x = R[8],  mx2x = R[9],  mn2y = R[10], mx2y = R[11];
        const float mn3x = R[12], mx3x = R[13], mn3y = R[14], mx3y = R[15];
        {   // cid=2 vs rb=bounds[3]
            const float dx = mx3x - mn3x + 1e-7f, dy = mx3y - mn3y + 1e-7f;
            const float xc0 = (mn2x - mn3x) / dx, xc1 = (mx2x - mn3x) / dx;
            const float yc0 = (mn2y - mn3y) / dy, yc1 = (mx2y - mn3y) / dy;
            const float v0 = (xc0 < 0.1f || xc0 > 0.9f || yc0 < 0.1f || yc0 > 0.9f) ? 1.f : 0.f;
            const float v1 = (xc1 < 0.1f || xc1 > 0.9f || yc1 < 0.1f || yc1 > 0.9f) ? 1.f : 0.f;
            w[2] += 50.f * 0.5f * (v0 + v1);
        }
        {   // cid=3 vs rb=bounds[2]
            const float dx = mx2x - mn2x + 1e-7f, dy = mx2y - mn2y + 1e-7f;
            const float xc0 = (mn3x - mn2x) / dx, xc1 = (mx3x - mn2x) / dx;
            const float yc0 = (mn3y - mn2y) / dy, yc1 = (mx3y - mn2y) / dy;
            const float v0 = (xc0 < 0.1f || xc0 > 0.9f || yc0 < 0.1f || yc0 > 0.9f) ? 1.f : 0.f;
            const float v1 = (xc1 < 0.1f || xc1 > 0.9f || yc1 < 0.1f || yc1 > 0.9f) ? 1.f : 0.f;
            w[3] += 50.f * 0.5f * (v0 + v1);
        }
#pragma unroll
        for (int c = 0; c < 5; ++c)
            w[c] = fminf(fmaxf(w[c], 0.1f), 10.f);
    }
    float wsumc[5];
#pragma unroll
    for (int c = 0; c < 5; ++c) wsumc[c] = wred_sum(w[c]);

    if (lane == 0) {
        float dist[5], cw[5], s = 0.f;
#pragma unroll
        for (int c = 0; c < 5; ++c) {
            dist[c] = sm[11 + c];
            cw[c] = 1.f / (sqrtf(dist[c]) + 1e-7f);
            s += cw[c];
        }
        float wf[5], wsum = 0.f, W = 0.f, nllnum = 0.f, Ssum = 0.f;
#pragma unroll
        for (int c = 0; c < 5; ++c) {
            cw[c] = cw[c] / s * 5.f;
            wf[c] = (wsumc[c] / 32.f) * cw[c];
            wsum += wf[c] * dist[c];
            W += wf[c];
            nllnum += wf[c] * sm[5 + c];
            Ssum += wf[c] * sm[c];
        }
        const float nll = nllnum / wsum;
        const float smooth = (W * sm[10] - Ssum) / wsum;
        out[0] = 0.8f * nll + 0.04f * smooth;
    }
}

extern "C" void kernel_launch(void* const* d_in, const int* in_sizes, int n_in,
                              void* d_out, int out_size, void* d_ws, size_t ws_size,
                              hipStream_t stream) {
    const float* outputs = (const float*)d_in[0];
    const int*   labels  = (const int*)d_in[1];
    const float* points  = (const float*)d_in[2];
    float* out = (float*)d_out;

    const size_t S2N = 16 + 24 * BATCH;  // 784
    int bpb = 256;  // ITERS = 256/bpb; shrink if workspace too small
    while (bpb > 1 &&
           (size_t)(27 + 9) * 4 * BATCH * (size_t)bpb + S2N * 4 + 4 > ws_size)
        bpb >>= 1;
    const int nblk = BATCH * bpb;
    const int iters = 256 / bpb;

    float* pf = (float*)d_ws;
    unsigned int* pi = (unsigned int*)(pf + (size_t)27 * nblk);
    float* s2 = (float*)(pi + (size_t)9 * nblk);
    unsigned int* counter = (unsigned int*)(s2 + S2N);

    switch (iters) {
        case 1:  bsl_main<1><<<nblk, 256, 0, stream>>>(outputs, labels, points, pf, pi, bpb, counter); break;
        case 2:  bsl_main<2><<<nblk, 256, 0, stream>>>(outputs, labels, points, pf, pi, bpb, counter); break;
        case 4:  bsl_main<4><<<nblk, 256, 0, stream>>>(outputs, labels, points, pf, pi, bpb, counter); break;
        case 8:  bsl_main<8><<<nblk, 256, 0, stream>>>(outputs, labels, points, pf, pi, bpb, counter); break;
        default: bsl_main<16><<<nblk, 256, 0, stream>>>(outputs, labels, points, pf, pi, bpb, counter); break;
    }
    bsl_reduce<<<(int)S2N, 64, 0, stream>>>(pf, pi, bpb, s2, counter, out);
}

// Round 4
// 81.437 us; speedup vs baseline: 1.4483x; 1.4483x over previous
//
#include <hip/hip_runtime.h>
#include <math.h>

#define NPTS 262144
#define BATCH 32

// ---------- wave (64-lane) reductions ----------
__device__ __forceinline__ float wred_sum(float v) {
#pragma unroll
    for (int o = 32; o; o >>= 1) v += __shfl_down(v, o);
    return v;
}
__device__ __forceinline__ unsigned wred_usum(unsigned v) {
#pragma unroll
    for (int o = 32; o; o >>= 1) v += __shfl_down(v, o);
    return v;
}
__device__ __forceinline__ float wred_min(float v) {
#pragma unroll
    for (int o = 32; o; o >>= 1) v = fminf(v, __shfl_down(v, o));
    return v;
}
__device__ __forceinline__ float wred_max(float v) {
#pragma unroll
    for (int o = 32; o; o >>= 1) v = fmaxf(v, __shfl_down(v, o));
    return v;
}

// Partial layout in d_ws:
//   float pf[27][nblk] : 0..4 S[c], 5..9 T[c], 10 lse_sum,
//                        11..14 gt z-sum (cls1..4), 15..18 pred z-sum,
//                        19..26 {mn2x,mx2x,mn2y,mx2y,mn3x,mx3x,mn3y,mx3y}
//   uint  pi[9][nblk]  : 0..4 bincount (rows 1..4 double as GT counts), 5..8 pred cnt
// Stage-2: float s2[16 + 24*BATCH]
//   s2[0..10] global S,T,lse; s2[11..15] dist (bincount, exact in f32)
//   s2[16 + b*24 + f], f: 0..3 gtz, 4..7 prz, 8..15 minmax, 16..19 gtc, 20..23 prc

__global__ __launch_bounds__(256) void bsl_main(
    const float* __restrict__ outputs, const int* __restrict__ labels,
    const float* __restrict__ points, float* __restrict__ pf,
    unsigned int* __restrict__ pi, int bpb, int iters,
    unsigned int* __restrict__ counter)
{
    const int blk = blockIdx.x;
    const int nblk = gridDim.x;
    const int b = blk / bpb;
    const int seg = blk % bpb;
    const int seg_start = seg * (iters * 1024);
    const int tid = threadIdx.x;

    if (blk == 0 && tid == 0) *counter = 0u;  // reset for bsl_reduce (stream-ordered)

    float S[5] = {0, 0, 0, 0, 0};
    float T[5] = {0, 0, 0, 0, 0};
    float lseacc = 0.f;
    float gtz[4] = {0, 0, 0, 0};
    float prz[4] = {0, 0, 0, 0};
    const float INF = __int_as_float(0x7f800000);
    float mn2x = INF, mx2x = -INF, mn2y = INF, mx2y = -INF;
    float mn3x = INF, mx3x = -INF, mn3y = INF, mx3y = -INF;
    unsigned bc[5] = {0, 0, 0, 0, 0}, prc[4] = {0, 0, 0, 0};

    const float* obase = outputs + (size_t)b * 5 * NPTS;
    const int*   lbase = labels + (size_t)b * NPTS;
    const float* pbase = points + (size_t)b * NPTS * 3;

    for (int it = 0; it < iters; ++it) {
        const int n = seg_start + it * 1024 + tid * 4;
        float4 L[5];
#pragma unroll
        for (int c = 0; c < 5; ++c)
            L[c] = *(const float4*)(obase + (size_t)c * NPTS + n);
        const int4 lab = *(const int4*)(lbase + n);
        const float4* pp = (const float4*)(pbase + (size_t)n * 3);
        const float4 p0 = pp[0], p1 = pp[1], p2 = pp[2];
        const float xs[4] = {p0.x, p0.w, p1.z, p2.y};
        const float ys[4] = {p0.y, p1.x, p1.w, p2.z};
        const float zs[4] = {p0.z, p1.y, p2.x, p2.w};
        const int   lb[4] = {lab.x, lab.y, lab.z, lab.w};
#pragma unroll
        for (int j = 0; j < 4; ++j) {
            float v[5];
#pragma unroll
            for (int c = 0; c < 5; ++c) v[c] = ((const float*)&L[c])[j];
            // first-max argmax (JAX tie-break semantics)
            float best = v[0]; int pred = 0;
#pragma unroll
            for (int c = 1; c < 5; ++c)
                if (v[c] > best) { best = v[c]; pred = c; }
            float e = 0.f;
#pragma unroll
            for (int c = 0; c < 5; ++c) e += __expf(v[c] - best);
            const float lse = best + __logf(e);
            lseacc += lse;
            const int y = lb[j];
#pragma unroll
            for (int c = 0; c < 5; ++c) {
                S[c] += v[c];
                const bool is = (y == c);
                T[c] += is ? (lse - v[c]) : 0.f;
                bc[c] += is ? 1u : 0u;
            }
            const float z = zs[j];
#pragma unroll
            for (int k = 0; k < 4; ++k) {
                const bool gy = (y == k + 1), py = (pred == k + 1);
                gtz[k] += gy ? z : 0.f;
                prz[k] += py ? z : 0.f;
                prc[k] += py ? 1u : 0u;
            }
            const float x = xs[j], yv = ys[j];
            // reference: mp = points*mask -> zeros included in min/max
            const float a2x = (pred == 2) ? x : 0.f;
            const float a2y = (pred == 2) ? yv : 0.f;
            const float a3x = (pred == 3) ? x : 0.f;
            const float a3y = (pred == 3) ? yv : 0.f;
            mn2x = fminf(mn2x, a2x); mx2x = fmaxf(mx2x, a2x);
            mn2y = fminf(mn2y, a2y); mx2y = fmaxf(mx2y, a2y);
            mn3x = fminf(mn3x, a3x); mx3x = fmaxf(mx3x, a3x);
            mn3y = fminf(mn3y, a3y); mx3y = fmaxf(mx3y, a3y);
        }
    }

    float fv[27] = {S[0], S[1], S[2], S[3], S[4],
                    T[0], T[1], T[2], T[3], T[4],
                    lseacc,
                    gtz[0], gtz[1], gtz[2], gtz[3],
                    prz[0], prz[1], prz[2], prz[3],
                    mn2x, mx2x, mn2y, mx2y, mn3x, mx3x, mn3y, mx3y};
    unsigned iv[9] = {bc[0], bc[1], bc[2], bc[3], bc[4],
                      prc[0], prc[1], prc[2], prc[3]};

    __shared__ float sf[4][27];
    __shared__ unsigned si[4][9];
    const int wid = tid >> 6, lane = tid & 63;
#pragma unroll
    for (int vdx = 0; vdx < 27; ++vdx) {
        float r;
        if (vdx < 19) r = wred_sum(fv[vdx]);
        else if (((vdx - 19) & 1) == 0) r = wred_min(fv[vdx]);
        else r = wred_max(fv[vdx]);
        if (lane == 0) sf[wid][vdx] = r;
    }
#pragma unroll
    for (int vdx = 0; vdx < 9; ++vdx) {
        unsigned r = wred_usum(iv[vdx]);
        if (lane == 0) si[wid][vdx] = r;
    }
    __syncthreads();
    if (tid == 0) {
#pragma unroll
        for (int vdx = 0; vdx < 27; ++vdx) {
            float r;
            if (vdx < 19) r = sf[0][vdx] + sf[1][vdx] + sf[2][vdx] + sf[3][vdx];
            else if (((vdx - 19) & 1) == 0)
                r = fminf(fminf(sf[0][vdx], sf[1][vdx]), fminf(sf[2][vdx], sf[3][vdx]));
            else
                r = fmaxf(fmaxf(sf[0][vdx], sf[1][vdx]), fmaxf(sf[2][vdx], sf[3][vdx]));
            pf[(size_t)vdx * nblk + blk] = r;
        }
#pragma unroll
        for (int vdx = 0; vdx < 9; ++vdx)
            pi[(size_t)vdx * nblk + blk] = si[0][vdx] + si[1][vdx] + si[2][vdx] + si[3][vdx];
    }
}

// One task per block (784 blocks, all concurrent), 256 threads so the big
// global rows are 2 independent float4 loads/thread. Last-done block runs
// the tiny finalize (device-scope atomic + threadfence release/acquire).
__global__ __launch_bounds__(256) void bsl_reduce(
    const float* __restrict__ pf, const unsigned int* __restrict__ pi,
    int bpb, float* __restrict__ s2, unsigned int* __restrict__ counter,
    float* __restrict__ out)
{
    const int nblk = BATCH * bpb;
    const int t = blockIdx.x;
    const int tid = threadIdx.x;
    const int wid = tid >> 6, lane = tid & 63;
    const float INF = __int_as_float(0x7f800000);
    __shared__ float red[4];
    __shared__ int isLast;
    __shared__ float sm[16 + 24 * BATCH];

    float result = 0.f;
    if (t < 11) {                      // global float sums over nblk
        const float4* p4 = (const float4*)(pf + (size_t)t * nblk);
        const int n4 = nblk >> 2;
        float s = 0.f;
        for (int i = tid; i < n4; i += 256) {
            const float4 v = p4[i];
            s += (v.x + v.y) + (v.z + v.w);
        }
        s = wred_sum(s);
        if (lane == 0) red[wid] = s;
        __syncthreads();
        result = red[0] + red[1] + red[2] + red[3];
    } else if (t < 16) {               // global bincount (exact in f32)
        const uint4* p4 = (const uint4*)(pi + (size_t)(t - 11) * nblk);
        const int n4 = nblk >> 2;
        float s = 0.f;
        for (int i = tid; i < n4; i += 256) {
            const uint4 u = p4[i];
            s += (float)u.x + (float)u.y + (float)u.z + (float)u.w;
        }
        s = wred_sum(s);
        if (lane == 0) red[wid] = s;
        __syncthreads();
        result = red[0] + red[1] + red[2] + red[3];
    } else {                           // per-batch tasks: wave 0 only
        const int u = t - 16;
        const int b = u / 24;
        const int f = u % 24;
        const int base = b * bpb;
        if (wid == 0) {
            if (f < 8) {
                float s = 0.f;
                for (int i = lane; i < bpb; i += 64) s += pf[(size_t)(11 + f) * nblk + base + i];
                result = wred_sum(s);
            } else if (f < 16) {
                const int g = f - 8;
                const bool ismin = ((g & 1) == 0);
                float s = ismin ? INF : -INF;
                for (int i = lane; i < bpb; i += 64) {
                    const float x = pf[(size_t)(19 + g) * nblk + base + i];
                    s = ismin ? fminf(s, x) : fmaxf(s, x);
                }
                result = ismin ? wred_min(s) : wred_max(s);
            } else {
                const int g = f - 16;
                // g<4: per-batch GT count == bincount rows 1..4
                const int row = (g < 4) ? (1 + g) : (5 + (g - 4));
                float s = 0.f;
                for (int i = lane; i < bpb; i += 64) s += (float)pi[(size_t)row * nblk + base + i];
                result = wred_sum(s);
            }
        }
    }

    // ---- publish + last-block-done finalize ----
    if (tid == 0) {
        s2[t] = result;
        __threadfence();                       // release s2[t]
        const unsigned old = atomicAdd(counter, 1u);
        isLast = (old == (unsigned)(gridDim.x - 1)) ? 1 : 0;
    }
    __syncthreads();
    if (!isLast) return;
    __threadfence();                           // acquire all s2 writes

    for (int i = tid; i < 16 + 24 * BATCH; i += 256) sm[i] = s2[i];
    __syncthreads();
    if (wid != 0) return;                      // finalize on wave 0

    const float BASE_W[5] = {0.8f, 2.0f, 1.5f, 1.5f, 3.5f};
    const int pc[12]  = {1, 1, 1, 2, 2, 2, 3, 3, 3, 4, 4, 4};
    const int prf[12] = {2, 3, 4, 1, 3, 4, 1, 2, 4, 1, 2, 3};
    const float ps[12] = {-1.f, -1.f, -1.f, 1.f, -1.f, -1.f, 1.f, 1.f, -1.f, 1.f, 1.f, 1.f};

    // lane b (< BATCH) computes batch b's clipped weights; others contribute 0
    float w[5] = {0, 0, 0, 0, 0};
    if (lane < BATCH) {
        const float* R = sm + 16 + lane * 24;
        for (int c = 0; c < 5; ++c) w[c] = BASE_W[c];
        float gtm[4], prm[4];
        bool gv[4], pv[4];
#pragma unroll
        for (int k = 0; k < 4; ++k) {
            const float c1 = R[16 + k];
            gv[k] = (c1 > 0.f);
            gtm[k] = R[k] / fmaxf(c1, 1.f);
            const float c2 = R[20 + k];
            pv[k] = (c2 > 0.f);
            prm[k] = R[4 + k] / fmaxf(c2, 1.f);
        }
#pragma unroll
        for (int p = 0; p < 12; ++p) {
            const int cid = pc[p], ref = prf[p];
            float add = 0.f;
            if (pv[cid - 1] && gv[ref - 1]) {
                const float diff = ps[p] * (prm[cid - 1] - gtm[ref - 1]);
                add = 50.f / (1.f + expf(10.f * diff));  // ALPHA*sigmoid(-10*diff)
            }
            w[cid] += add;
            w[ref] += 0.3f * add;
        }
        const float mn2x = R[8],  mx2x = R[9],  mn2y = R[10], mx2y = R[11];
        const float mn3x = R[12], mx3x = R[13], mn3y = R[14], mx3y = R[15];
        {   // cid=2 vs rb=bounds[3]
            const float dx = mx3x - mn3x + 1e-7f, dy = mx3y - mn3y + 1e-7f;
            const float xc0 = (mn2x - mn3x) / dx, xc1 = (mx2x - mn3x) / dx;
            const float yc0 = (mn2y - mn3y) / dy, yc1 = (mx2y - mn3y) / dy;
            const float v0 = (xc0 < 0.1f || xc0 > 0.9f || yc0 < 0.1f || yc0 > 0.9f) ? 1.f : 0.f;
            const float v1 = (xc1 < 0.1f || xc1 > 0.9f || yc1 < 0.1f || yc1 > 0.9f) ? 1.f : 0.f;
            w[2] += 50.f * 0.5f * (v0 + v1);
        }
        {   // cid=3 vs rb=bounds[2]
            const float dx = mx2x - mn2x + 1e-7f, dy = mx2y - mn2y + 1e-7f;
            const float xc0 = (mn3x - mn2x) / dx, xc1 = (mx3x - mn2x) / dx;
            const float yc0 = (mn3y - mn2y) / dy, yc1 = (mx3y - mn2y) / dy;
            const float v0 = (xc0 < 0.1f || xc0 > 0.9f || yc0 < 0.1f || yc0 > 0.9f) ? 1.f : 0.f;
            const float v1 = (xc1 < 0.1f || xc1 > 0.9f || yc1 < 0.1f || yc1 > 0.9f) ? 1.f : 0.f;
            w[3] += 50.f * 0.5f * (v0 + v1);
        }
#pragma unroll
        for (int c = 0; c < 5; ++c)
            w[c] = fminf(fmaxf(w[c], 0.1f), 10.f);
    }
    float wsumc[5];
#pragma unroll
    for (int c = 0; c < 5; ++c) wsumc[c] = wred_sum(w[c]);

    if (lane == 0) {
        float dist[5], cw[5], s = 0.f;
#pragma unroll
        for (int c = 0; c < 5; ++c) {
            dist[c] = sm[11 + c];
            cw[c] = 1.f / (sqrtf(dist[c]) + 1e-7f);
            s += cw[c];
        }
        float wf[5], wsum = 0.f, W = 0.f, nllnum = 0.f, Ssum = 0.f;
#pragma unroll
        for (int c = 0; c < 5; ++c) {
            cw[c] = cw[c] / s * 5.f;
            wf[c] = (wsumc[c] / 32.f) * cw[c];
            wsum += wf[c] * dist[c];
            W += wf[c];
            nllnum += wf[c] * sm[5 + c];
            Ssum += wf[c] * sm[c];
        }
        const float nll = nllnum / wsum;
        const float smooth = (W * sm[10] - Ssum) / wsum;
        out[0] = 0.8f * nll + 0.04f * smooth;
    }
}

extern "C" void kernel_launch(void* const* d_in, const int* in_sizes, int n_in,
                              void* d_out, int out_size, void* d_ws, size_t ws_size,
                              hipStream_t stream) {
    const float* outputs = (const float*)d_in[0];
    const int*   labels  = (const int*)d_in[1];
    const float* points  = (const float*)d_in[2];
    float* out = (float*)d_out;

    const size_t S2N = 16 + 24 * BATCH;  // 784
    int bpb = 64;  // blocks per batch (round-2 known-good config)
    while (bpb > 1 &&
           (size_t)(27 + 9) * 4 * BATCH * (size_t)bpb + S2N * 4 + 4 > ws_size)
        bpb >>= 1;
    const int nblk = BATCH * bpb;
    const int iters = NPTS / (bpb * 1024);

    float* pf = (float*)d_ws;
    unsigned int* pi = (unsigned int*)(pf + (size_t)27 * nblk);
    float* s2 = (float*)(pi + (size_t)9 * nblk);
    unsigned int* counter = (unsigned int*)(s2 + S2N);

    bsl_main<<<nblk, 256, 0, stream>>>(outputs, labels, points, pf, pi, bpb, iters, counter);
    bsl_reduce<<<(int)S2N, 256, 0, stream>>>(pf, pi, bpb, s2, counter, out);
}

// Round 5
// 74.872 us; speedup vs baseline: 1.5753x; 1.0877x over previous
//
#include <hip/hip_runtime.h>
#include <math.h>

#define NPTS 262144
#define BATCH 32

// ---------- wave (64-lane) reductions ----------
__device__ __forceinline__ float wred_sum(float v) {
#pragma unroll
    for (int o = 32; o; o >>= 1) v += __shfl_down(v, o);
    return v;
}
__device__ __forceinline__ unsigned wred_usum(unsigned v) {
#pragma unroll
    for (int o = 32; o; o >>= 1) v += __shfl_down(v, o);
    return v;
}
__device__ __forceinline__ float wred_min(float v) {
#pragma unroll
    for (int o = 32; o; o >>= 1) v = fminf(v, __shfl_down(v, o));
    return v;
}
__device__ __forceinline__ float wred_max(float v) {
#pragma unroll
    for (int o = 32; o; o >>= 1) v = fmaxf(v, __shfl_down(v, o));
    return v;
}

// Partial layout in d_ws:
//   float pf[27][nblk] : 0..4 S[c], 5..9 T[c], 10 lse_sum,
//                        11..14 gt z-sum (cls1..4), 15..18 pred z-sum,
//                        19..26 {mn2x,mx2x,mn2y,mx2y,mn3x,mx3x,mn3y,mx3y}
//   uint  pi[9][nblk]  : 0..4 bincount (rows 1..4 double as GT counts), 5..8 pred cnt

__global__ __launch_bounds__(256) void bsl_main(
    const float* __restrict__ outputs, const int* __restrict__ labels,
    const float* __restrict__ points, float* __restrict__ pf,
    unsigned int* __restrict__ pi, int bpb, int iters)
{
    const int blk = blockIdx.x;
    const int nblk = gridDim.x;
    const int b = blk / bpb;
    const int seg = blk % bpb;
    const int seg_start = seg * (iters * 1024);
    const int tid = threadIdx.x;

    float S[5] = {0, 0, 0, 0, 0};
    float T[5] = {0, 0, 0, 0, 0};
    float lseacc = 0.f;
    float gtz[4] = {0, 0, 0, 0};
    float prz[4] = {0, 0, 0, 0};
    const float INF = __int_as_float(0x7f800000);
    float mn2x = INF, mx2x = -INF, mn2y = INF, mx2y = -INF;
    float mn3x = INF, mx3x = -INF, mn3y = INF, mx3y = -INF;
    unsigned bc[5] = {0, 0, 0, 0, 0}, prc[4] = {0, 0, 0, 0};

    const float* obase = outputs + (size_t)b * 5 * NPTS;
    const int*   lbase = labels + (size_t)b * NPTS;
    const float* pbase = points + (size_t)b * NPTS * 3;

    for (int it = 0; it < iters; ++it) {
        const int n = seg_start + it * 1024 + tid * 4;
        float4 L[5];
#pragma unroll
        for (int c = 0; c < 5; ++c)
            L[c] = *(const float4*)(obase + (size_t)c * NPTS + n);
        const int4 lab = *(const int4*)(lbase + n);
        const float4* pp = (const float4*)(pbase + (size_t)n * 3);
        const float4 p0 = pp[0], p1 = pp[1], p2 = pp[2];
        const float xs[4] = {p0.x, p0.w, p1.z, p2.y};
        const float ys[4] = {p0.y, p1.x, p1.w, p2.z};
        const float zs[4] = {p0.z, p1.y, p2.x, p2.w};
        const int   lb[4] = {lab.x, lab.y, lab.z, lab.w};
#pragma unroll
        for (int j = 0; j < 4; ++j) {
            float v[5];
#pragma unroll
            for (int c = 0; c < 5; ++c) v[c] = ((const float*)&L[c])[j];
            // first-max argmax (JAX tie-break semantics)
            float best = v[0]; int pred = 0;
#pragma unroll
            for (int c = 1; c < 5; ++c)
                if (v[c] > best) { best = v[c]; pred = c; }
            float e = 0.f;
#pragma unroll
            for (int c = 0; c < 5; ++c) e += __expf(v[c] - best);
            const float lse = best + __logf(e);
            lseacc += lse;
            const int y = lb[j];
#pragma unroll
            for (int c = 0; c < 5; ++c) {
                S[c] += v[c];
                const bool is = (y == c);
                T[c] += is ? (lse - v[c]) : 0.f;
                bc[c] += is ? 1u : 0u;
            }
            const float z = zs[j];
#pragma unroll
            for (int k = 0; k < 4; ++k) {
                const bool gy = (y == k + 1), py = (pred == k + 1);
                gtz[k] += gy ? z : 0.f;
                prz[k] += py ? z : 0.f;
                prc[k] += py ? 1u : 0u;
            }
            const float x = xs[j], yv = ys[j];
            // reference: mp = points*mask -> zeros included in min/max
            const float a2x = (pred == 2) ? x : 0.f;
            const float a2y = (pred == 2) ? yv : 0.f;
            const float a3x = (pred == 3) ? x : 0.f;
            const float a3y = (pred == 3) ? yv : 0.f;
            mn2x = fminf(mn2x, a2x); mx2x = fmaxf(mx2x, a2x);
            mn2y = fminf(mn2y, a2y); mx2y = fmaxf(mx2y, a2y);
            mn3x = fminf(mn3x, a3x); mx3x = fmaxf(mx3x, a3x);
            mn3y = fminf(mn3y, a3y); mx3y = fmaxf(mx3y, a3y);
        }
    }

    float fv[27] = {S[0], S[1], S[2], S[3], S[4],
                    T[0], T[1], T[2], T[3], T[4],
                    lseacc,
                    gtz[0], gtz[1], gtz[2], gtz[3],
                    prz[0], prz[1], prz[2], prz[3],
                    mn2x, mx2x, mn2y, mx2y, mn3x, mx3x, mn3y, mx3y};
    unsigned iv[9] = {bc[0], bc[1], bc[2], bc[3], bc[4],
                      prc[0], prc[1], prc[2], prc[3]};

    __shared__ float sf[4][27];
    __shared__ unsigned si[4][9];
    const int wid = tid >> 6, lane = tid & 63;
#pragma unroll
    for (int vdx = 0; vdx < 27; ++vdx) {
        float r;
        if (vdx < 19) r = wred_sum(fv[vdx]);
        else if (((vdx - 19) & 1) == 0) r = wred_min(fv[vdx]);
        else r = wred_max(fv[vdx]);
        if (lane == 0) sf[wid][vdx] = r;
    }
#pragma unroll
    for (int vdx = 0; vdx < 9; ++vdx) {
        unsigned r = wred_usum(iv[vdx]);
        if (lane == 0) si[wid][vdx] = r;
    }
    __syncthreads();
    if (tid == 0) {
#pragma unroll
        for (int vdx = 0; vdx < 27; ++vdx) {
            float r;
            if (vdx < 19) r = sf[0][vdx] + sf[1][vdx] + sf[2][vdx] + sf[3][vdx];
            else if (((vdx - 19) & 1) == 0)
                r = fminf(fminf(sf[0][vdx], sf[1][vdx]), fminf(sf[2][vdx], sf[3][vdx]));
            else
                r = fmaxf(fmaxf(sf[0][vdx], sf[1][vdx]), fmaxf(sf[2][vdx], sf[3][vdx]));
            pf[(size_t)vdx * nblk + blk] = r;
        }
#pragma unroll
        for (int vdx = 0; vdx < 9; ++vdx)
            pi[(size_t)vdx * nblk + blk] = si[0][vdx] + si[1][vdx] + si[2][vdx] + si[3][vdx];
    }
}

// Single-block reduce + finalize. 1024 threads = 16 waves.
// Stage A: wave w sums global row w (11 float rows + 5 bincount rows),
//          8 independent float4 loads/lane -> latency hidden by MLP.
// Stage B: thread t (<24*BATCH) handles one per-batch subtask,
//          bpb/4 independent float4 loads each.
// All results land in LDS; wave 0 runs the tiny closing math.
// Kernel boundary provides the device-wide fence (no threadfence/atomics).
__global__ __launch_bounds__(1024) void bsl_reduce_final(
    const float* __restrict__ pf, const unsigned int* __restrict__ pi,
    int bpb, float* __restrict__ out)
{
    const int nblk = BATCH * bpb;
    const int tid = threadIdx.x;
    const int wid = tid >> 6, lane = tid & 63;
    const float INF = __int_as_float(0x7f800000);
    __shared__ float sm[16 + 24 * BATCH];

    // ---- stage A: global rows, one wave per row ----
    {
        float s = 0.f;
        const int n4 = nblk >> 2;
        if (wid < 11) {
            const float4* p4 = (const float4*)(pf + (size_t)wid * nblk);
#pragma unroll 4
            for (int i = lane; i < n4; i += 64) {
                const float4 v = p4[i];
                s += (v.x + v.y) + (v.z + v.w);
            }
        } else {
            const uint4* p4 = (const uint4*)(pi + (size_t)(wid - 11) * nblk);
#pragma unroll 4
            for (int i = lane; i < n4; i += 64) {
                const uint4 u = p4[i];
                s += ((float)u.x + (float)u.y) + ((float)u.z + (float)u.w);
            }
        }
        s = wred_sum(s);
        if (lane == 0) sm[wid] = s;   // wid 0..10: S,T,lse ; 11..15: dist
    }

    // ---- stage B: per-batch subtasks, one thread each ----
    if (tid < 24 * BATCH) {
        const int b = tid / 24;
        const int f = tid % 24;
        const int base = b * bpb;
        const int q4 = bpb >> 2;
        float r;
        if (f < 8) {                      // gtz[4], prz[4]: sums of rows 11..18
            const float4* p4 = (const float4*)(pf + (size_t)(11 + f) * nblk + base);
            float s = 0.f;
#pragma unroll 8
            for (int i = 0; i < q4; ++i) {
                const float4 v = p4[i];
                s += (v.x + v.y) + (v.z + v.w);
            }
            r = s;
        } else if (f < 16) {              // minmax: rows 19..26
            const int g = f - 8;
            const bool ismin = ((g & 1) == 0);
            const float4* p4 = (const float4*)(pf + (size_t)(19 + g) * nblk + base);
            float s = ismin ? INF : -INF;
#pragma unroll 8
            for (int i = 0; i < q4; ++i) {
                const float4 v = p4[i];
                if (ismin) s = fminf(s, fminf(fminf(v.x, v.y), fminf(v.z, v.w)));
                else       s = fmaxf(s, fmaxf(fmaxf(v.x, v.y), fmaxf(v.z, v.w)));
            }
            r = s;
        } else {                          // gtc (== bincount rows 1..4), prc (rows 5..8)
            const int g = f - 16;
            const int row = (g < 4) ? (1 + g) : (5 + (g - 4));
            const uint4* p4 = (const uint4*)(pi + (size_t)row * nblk + base);
            float s = 0.f;
#pragma unroll 8
            for (int i = 0; i < q4; ++i) {
                const uint4 u = p4[i];
                s += ((float)u.x + (float)u.y) + ((float)u.z + (float)u.w);
            }
            r = s;
        }
        sm[16 + tid] = r;
    }
    __syncthreads();
    if (wid != 0) return;                 // finalize on wave 0

    const float BASE_W[5] = {0.8f, 2.0f, 1.5f, 1.5f, 3.5f};
    const int pc[12]  = {1, 1, 1, 2, 2, 2, 3, 3, 3, 4, 4, 4};
    const int prf[12] = {2, 3, 4, 1, 3, 4, 1, 2, 4, 1, 2, 3};
    const float ps[12] = {-1.f, -1.f, -1.f, 1.f, -1.f, -1.f, 1.f, 1.f, -1.f, 1.f, 1.f, 1.f};

    // lane b (< BATCH) computes batch b's clipped weights; others contribute 0
    float w[5] = {0, 0, 0, 0, 0};
    if (lane < BATCH) {
        const float* R = sm + 16 + lane * 24;
        for (int c = 0; c < 5; ++c) w[c] = BASE_W[c];
        float gtm[4], prm[4];
        bool gv[4], pv[4];
#pragma unroll
        for (int k = 0; k < 4; ++k) {
            const float c1 = R[16 + k];
            gv[k] = (c1 > 0.f);
            gtm[k] = R[k] / fmaxf(c1, 1.f);
            const float c2 = R[20 + k];
            pv[k] = (c2 > 0.f);
            prm[k] = R[4 + k] / fmaxf(c2, 1.f);
        }
#pragma unroll
        for (int p = 0; p < 12; ++p) {
            const int cid = pc[p], ref = prf[p];
            float add = 0.f;
            if (pv[cid - 1] && gv[ref - 1]) {
                const float diff = ps[p] * (prm[cid - 1] - gtm[ref - 1]);
                add = 50.f / (1.f + expf(10.f * diff));  // ALPHA*sigmoid(-10*diff)
            }
            w[cid] += add;
            w[ref] += 0.3f * add;
        }
        const float mn2x = R[8],  mx2x = R[9],  mn2y = R[10], mx2y = R[11];
        const float mn3x = R[12], mx3x = R[13], mn3y = R[14], mx3y = R[15];
        {   // cid=2 vs rb=bounds[3]
            const float dx = mx3x - mn3x + 1e-7f, dy = mx3y - mn3y + 1e-7f;
            const float xc0 = (mn2x - mn3x) / dx, xc1 = (mx2x - mn3x) / dx;
            const float yc0 = (mn2y - mn3y) / dy, yc1 = (mx2y - mn3y) / dy;
            const float v0 = (xc0 < 0.1f || xc0 > 0.9f || yc0 < 0.1f || yc0 > 0.9f) ? 1.f : 0.f;
            const float v1 = (xc1 < 0.1f || xc1 > 0.9f || yc1 < 0.1f || yc1 > 0.9f) ? 1.f : 0.f;
            w[2] += 50.f * 0.5f * (v0 + v1);
        }
        {   // cid=3 vs rb=bounds[2]
            const float dx = mx2x - mn2x + 1e-7f, dy = mx2y - mn2y + 1e-7f;
            const float xc0 = (mn3x - mn2x) / dx, xc1 = (mx3x - mn2x) / dx;
            const float yc0 = (mn3y - mn2y) / dy, yc1 = (mx3y - mn2y) / dy;
            const float v0 = (xc0 < 0.1f || xc0 > 0.9f || yc0 < 0.1f || yc0 > 0.9f) ? 1.f : 0.f;
            const float v1 = (xc1 < 0.1f || xc1 > 0.9f || yc1 < 0.1f || yc1 > 0.9f) ? 1.f : 0.f;
            w[3] += 50.f * 0.5f * (v0 + v1);
        }
#pragma unroll
        for (int c = 0; c < 5; ++c)
            w[c] = fminf(fmaxf(w[c], 0.1f), 10.f);
    }
    float wsumc[5];
#pragma unroll
    for (int c = 0; c < 5; ++c) wsumc[c] = wred_sum(w[c]);

    if (lane == 0) {
        float dist[5], cw[5], s = 0.f;
#pragma unroll
        for (int c = 0; c < 5; ++c) {
            dist[c] = sm[11 + c];
            cw[c] = 1.f / (sqrtf(dist[c]) + 1e-7f);
            s += cw[c];
        }
        float wf[5], wsum = 0.f, W = 0.f, nllnum = 0.f, Ssum = 0.f;
#pragma unroll
        for (int c = 0; c < 5; ++c) {
            cw[c] = cw[c] / s * 5.f;
            wf[c] = (wsumc[c] / 32.f) * cw[c];
            wsum += wf[c] * dist[c];
            W += wf[c];
            nllnum += wf[c] * sm[5 + c];
            Ssum += wf[c] * sm[c];
        }
        const float nll = nllnum / wsum;
        const float smooth = (W * sm[10] - Ssum) / wsum;
        out[0] = 0.8f * nll + 0.04f * smooth;
    }
}

extern "C" void kernel_launch(void* const* d_in, const int* in_sizes, int n_in,
                              void* d_out, int out_size, void* d_ws, size_t ws_size,
                              hipStream_t stream) {
    const float* outputs = (const float*)d_in[0];
    const int*   labels  = (const int*)d_in[1];
    const float* points  = (const float*)d_in[2];
    float* out = (float*)d_out;

    int bpb = 64;  // blocks per batch (round-2 known-good config)
    while (bpb > 4 &&
           (size_t)(27 + 9) * 4 * BATCH * (size_t)bpb > ws_size)
        bpb >>= 1;
    const int nblk = BATCH * bpb;
    const int iters = NPTS / (bpb * 1024);

    float* pf = (float*)d_ws;
    unsigned int* pi = (unsigned int*)(pf + (size_t)27 * nblk);

    bsl_main<<<nblk, 256, 0, stream>>>(outputs, labels, points, pf, pi, bpb, iters);
    bsl_reduce_final<<<1, 1024, 0, stream>>>(pf, pi, bpb, out);
}

// Round 6
// 64.168 us; speedup vs baseline: 1.8381x; 1.1668x over previous
//
#include <hip/hip_runtime.h>
#include <math.h>

#define NPTS 262144
#define BATCH 32

// ---------- wave (64-lane) reductions ----------
__device__ __forceinline__ float wred_sum(float v) {
#pragma unroll
    for (int o = 32; o; o >>= 1) v += __shfl_down(v, o);
    return v;
}
__device__ __forceinline__ unsigned wred_usum(unsigned v) {
#pragma unroll
    for (int o = 32; o; o >>= 1) v += __shfl_down(v, o);
    return v;
}
__device__ __forceinline__ float wred_min(float v) {
#pragma unroll
    for (int o = 32; o; o >>= 1) v = fminf(v, __shfl_down(v, o));
    return v;
}
__device__ __forceinline__ float wred_max(float v) {
#pragma unroll
    for (int o = 32; o; o >>= 1) v = fmaxf(v, __shfl_down(v, o));
    return v;
}

// Partial layout in d_ws (nblk = BATCH*bpb = 512 -> 72 KB total):
//   float pf[27][nblk] : 0..4 S[c], 5..9 T[c], 10 lse_sum,
//                        11..14 gt z-sum (cls1..4), 15..18 pred z-sum,
//                        19..26 {mn2x,mx2x,mn2y,mx2y,mn3x,mx3x,mn3y,mx3y}
//   uint  pi[9][nblk]  : 0..4 bincount (rows 1..4 double as GT counts), 5..8 pred cnt

__global__ __launch_bounds__(256) void bsl_main(
    const float* __restrict__ outputs, const int* __restrict__ labels,
    const float* __restrict__ points, float* __restrict__ pf,
    unsigned int* __restrict__ pi, int bpb, int iters)
{
    const int blk = blockIdx.x;
    const int nblk = gridDim.x;
    const int b = blk / bpb;
    const int seg = blk % bpb;
    const int seg_start = seg * (iters * 1024);
    const int tid = threadIdx.x;

    float S[5] = {0, 0, 0, 0, 0};
    float T[5] = {0, 0, 0, 0, 0};
    float lseacc = 0.f;
    float gtz[4] = {0, 0, 0, 0};
    float prz[4] = {0, 0, 0, 0};
    const float INF = __int_as_float(0x7f800000);
    float mn2x = INF, mx2x = -INF, mn2y = INF, mx2y = -INF;
    float mn3x = INF, mx3x = -INF, mn3y = INF, mx3y = -INF;
    unsigned bc[5] = {0, 0, 0, 0, 0}, prc[4] = {0, 0, 0, 0};

    const float* obase = outputs + (size_t)b * 5 * NPTS;
    const int*   lbase = labels + (size_t)b * NPTS;
    const float* pbase = points + (size_t)b * NPTS * 3;

    for (int it = 0; it < iters; ++it) {
        const int n = seg_start + it * 1024 + tid * 4;
        float4 L[5];
#pragma unroll
        for (int c = 0; c < 5; ++c)
            L[c] = *(const float4*)(obase + (size_t)c * NPTS + n);
        const int4 lab = *(const int4*)(lbase + n);
        const float4* pp = (const float4*)(pbase + (size_t)n * 3);
        const float4 p0 = pp[0], p1 = pp[1], p2 = pp[2];
        const float xs[4] = {p0.x, p0.w, p1.z, p2.y};
        const float ys[4] = {p0.y, p1.x, p1.w, p2.z};
        const float zs[4] = {p0.z, p1.y, p2.x, p2.w};
        const int   lb[4] = {lab.x, lab.y, lab.z, lab.w};
#pragma unroll
        for (int j = 0; j < 4; ++j) {
            float v[5];
#pragma unroll
            for (int c = 0; c < 5; ++c) v[c] = ((const float*)&L[c])[j];
            // first-max argmax (JAX tie-break semantics)
            float best = v[0]; int pred = 0;
#pragma unroll
            for (int c = 1; c < 5; ++c)
                if (v[c] > best) { best = v[c]; pred = c; }
            float e = 0.f;
#pragma unroll
            for (int c = 0; c < 5; ++c) e += __expf(v[c] - best);
            const float lse = best + __logf(e);
            lseacc += lse;
            const int y = lb[j];
#pragma unroll
            for (int c = 0; c < 5; ++c) {
                S[c] += v[c];
                const bool is = (y == c);
                T[c] += is ? (lse - v[c]) : 0.f;
                bc[c] += is ? 1u : 0u;
            }
            const float z = zs[j];
#pragma unroll
            for (int k = 0; k < 4; ++k) {
                const bool gy = (y == k + 1), py = (pred == k + 1);
                gtz[k] += gy ? z : 0.f;
                prz[k] += py ? z : 0.f;
                prc[k] += py ? 1u : 0u;
            }
            const float x = xs[j], yv = ys[j];
            // reference: mp = points*mask -> zeros included in min/max
            const float a2x = (pred == 2) ? x : 0.f;
            const float a2y = (pred == 2) ? yv : 0.f;
            const float a3x = (pred == 3) ? x : 0.f;
            const float a3y = (pred == 3) ? yv : 0.f;
            mn2x = fminf(mn2x, a2x); mx2x = fmaxf(mx2x, a2x);
            mn2y = fminf(mn2y, a2y); mx2y = fmaxf(mx2y, a2y);
            mn3x = fminf(mn3x, a3x); mx3x = fmaxf(mx3x, a3x);
            mn3y = fminf(mn3y, a3y); mx3y = fmaxf(mx3y, a3y);
        }
    }

    float fv[27] = {S[0], S[1], S[2], S[3], S[4],
                    T[0], T[1], T[2], T[3], T[4],
                    lseacc,
                    gtz[0], gtz[1], gtz[2], gtz[3],
                    prz[0], prz[1], prz[2], prz[3],
                    mn2x, mx2x, mn2y, mx2y, mn3x, mx3x, mn3y, mx3y};
    unsigned iv[9] = {bc[0], bc[1], bc[2], bc[3], bc[4],
                      prc[0], prc[1], prc[2], prc[3]};

    __shared__ float sf[4][27];
    __shared__ unsigned si[4][9];
    const int wid = tid >> 6, lane = tid & 63;
#pragma unroll
    for (int vdx = 0; vdx < 27; ++vdx) {
        float r;
        if (vdx < 19) r = wred_sum(fv[vdx]);
        else if (((vdx - 19) & 1) == 0) r = wred_min(fv[vdx]);
        else r = wred_max(fv[vdx]);
        if (lane == 0) sf[wid][vdx] = r;
    }
#pragma unroll
    for (int vdx = 0; vdx < 9; ++vdx) {
        unsigned r = wred_usum(iv[vdx]);
        if (lane == 0) si[wid][vdx] = r;
    }
    __syncthreads();
    if (tid == 0) {
#pragma unroll
        for (int vdx = 0; vdx < 27; ++vdx) {
            float r;
            if (vdx < 19) r = sf[0][vdx] + sf[1][vdx] + sf[2][vdx] + sf[3][vdx];
            else if (((vdx - 19) & 1) == 0)
                r = fminf(fminf(sf[0][vdx], sf[1][vdx]), fminf(sf[2][vdx], sf[3][vdx]));
            else
                r = fmaxf(fmaxf(sf[0][vdx], sf[1][vdx]), fmaxf(sf[2][vdx], sf[3][vdx]));
            pf[(size_t)vdx * nblk + blk] = r;
        }
#pragma unroll
        for (int vdx = 0; vdx < 9; ++vdx)
            pi[(size_t)vdx * nblk + blk] = si[0][vdx] + si[1][vdx] + si[2][vdx] + si[3][vdx];
    }
}

// Single-block reduce + finalize over a SMALL (72 KB) partial matrix.
// One CU sustains only ~25 GB/s from HBM, so keeping the partials tiny is
// what makes a single-block tail viable (~3 us streaming + 1 latency round).
// Stage A: wave w sums global row w (11 float rows + 5 bincount rows).
// Stage B: thread t (<24*BATCH) handles one per-batch subtask (bpb els).
// Kernel boundary provides the device-wide fence (no threadfence/atomics).
__global__ __launch_bounds__(1024) void bsl_reduce_final(
    const float* __restrict__ pf, const unsigned int* __restrict__ pi,
    int bpb, float* __restrict__ out)
{
    const int nblk = BATCH * bpb;
    const int tid = threadIdx.x;
    const int wid = tid >> 6, lane = tid & 63;
    const float INF = __int_as_float(0x7f800000);
    __shared__ float sm[16 + 24 * BATCH];

    // ---- stage A: global rows, one wave per row ----
    {
        float s = 0.f;
        const int n4 = nblk >> 2;
        if (wid < 11) {
            const float4* p4 = (const float4*)(pf + (size_t)wid * nblk);
#pragma unroll 2
            for (int i = lane; i < n4; i += 64) {
                const float4 v = p4[i];
                s += (v.x + v.y) + (v.z + v.w);
            }
        } else {
            const uint4* p4 = (const uint4*)(pi + (size_t)(wid - 11) * nblk);
#pragma unroll 2
            for (int i = lane; i < n4; i += 64) {
                const uint4 u = p4[i];
                s += ((float)u.x + (float)u.y) + ((float)u.z + (float)u.w);
            }
        }
        s = wred_sum(s);
        if (lane == 0) sm[wid] = s;   // wid 0..10: S,T,lse ; 11..15: dist
    }

    // ---- stage B: per-batch subtasks, one thread each ----
    if (tid < 24 * BATCH) {
        const int b = tid / 24;
        const int f = tid % 24;
        const int base = b * bpb;
        const int q4 = bpb >> 2;
        float r;
        if (f < 8) {                      // gtz[4], prz[4]: sums of rows 11..18
            const float4* p4 = (const float4*)(pf + (size_t)(11 + f) * nblk + base);
            float s = 0.f;
#pragma unroll 4
            for (int i = 0; i < q4; ++i) {
                const float4 v = p4[i];
                s += (v.x + v.y) + (v.z + v.w);
            }
            r = s;
        } else if (f < 16) {              // minmax: rows 19..26
            const int g = f - 8;
            const bool ismin = ((g & 1) == 0);
            const float4* p4 = (const float4*)(pf + (size_t)(19 + g) * nblk + base);
            float s = ismin ? INF : -INF;
#pragma unroll 4
            for (int i = 0; i < q4; ++i) {
                const float4 v = p4[i];
                if (ismin) s = fminf(s, fminf(fminf(v.x, v.y), fminf(v.z, v.w)));
                else       s = fmaxf(s, fmaxf(fmaxf(v.x, v.y), fmaxf(v.z, v.w)));
            }
            r = s;
        } else {                          // gtc (== bincount rows 1..4), prc (rows 5..8)
            const int g = f - 16;
            const int row = (g < 4) ? (1 + g) : (5 + (g - 4));
            const uint4* p4 = (const uint4*)(pi + (size_t)row * nblk + base);
            float s = 0.f;
#pragma unroll 4
            for (int i = 0; i < q4; ++i) {
                const uint4 u = p4[i];
                s += ((float)u.x + (float)u.y) + ((float)u.z + (float)u.w);
            }
            r = s;
        }
        sm[16 + tid] = r;
    }
    __syncthreads();
    if (wid != 0) return;                 // finalize on wave 0

    const float BASE_W[5] = {0.8f, 2.0f, 1.5f, 1.5f, 3.5f};
    const int pc[12]  = {1, 1, 1, 2, 2, 2, 3, 3, 3, 4, 4, 4};
    const int prf[12] = {2, 3, 4, 1, 3, 4, 1, 2, 4, 1, 2, 3};
    const float ps[12] = {-1.f, -1.f, -1.f, 1.f, -1.f, -1.f, 1.f, 1.f, -1.f, 1.f, 1.f, 1.f};

    // lane b (< BATCH) computes batch b's clipped weights; others contribute 0
    float w[5] = {0, 0, 0, 0, 0};
    if (lane < BATCH) {
        const float* R = sm + 16 + lane * 24;
        for (int c = 0; c < 5; ++c) w[c] = BASE_W[c];
        float gtm[4], prm[4];
        bool gv[4], pv[4];
#pragma unroll
        for (int k = 0; k < 4; ++k) {
            const float c1 = R[16 + k];
            gv[k] = (c1 > 0.f);
            gtm[k] = R[k] / fmaxf(c1, 1.f);
            const float c2 = R[20 + k];
            pv[k] = (c2 > 0.f);
            prm[k] = R[4 + k] / fmaxf(c2, 1.f);
        }
#pragma unroll
        for (int p = 0; p < 12; ++p) {
            const int cid = pc[p], ref = prf[p];
            float add = 0.f;
            if (pv[cid - 1] && gv[ref - 1]) {
                const float diff = ps[p] * (prm[cid - 1] - gtm[ref - 1]);
                add = 50.f / (1.f + expf(10.f * diff));  // ALPHA*sigmoid(-10*diff)
            }
            w[cid] += add;
            w[ref] += 0.3f * add;
        }
        const float mn2x = R[8],  mx2x = R[9],  mn2y = R[10], mx2y = R[11];
        const float mn3x = R[12], mx3x = R[13], mn3y = R[14], mx3y = R[15];
        {   // cid=2 vs rb=bounds[3]
            const float dx = mx3x - mn3x + 1e-7f, dy = mx3y - mn3y + 1e-7f;
            const float xc0 = (mn2x - mn3x) / dx, xc1 = (mx2x - mn3x) / dx;
            const float yc0 = (mn2y - mn3y) / dy, yc1 = (mx2y - mn3y) / dy;
            const float v0 = (xc0 < 0.1f || xc0 > 0.9f || yc0 < 0.1f || yc0 > 0.9f) ? 1.f : 0.f;
            const float v1 = (xc1 < 0.1f || xc1 > 0.9f || yc1 < 0.1f || yc1 > 0.9f) ? 1.f : 0.f;
            w[2] += 50.f * 0.5f * (v0 + v1);
        }
        {   // cid=3 vs rb=bounds[2]
            const float dx = mx2x - mn2x + 1e-7f, dy = mx2y - mn2y + 1e-7f;
            const float xc0 = (mn3x - mn2x) / dx, xc1 = (mx3x - mn2x) / dx;
            const float yc0 = (mn3y - mn2y) / dy, yc1 = (mx3y - mn2y) / dy;
            const float v0 = (xc0 < 0.1f || xc0 > 0.9f || yc0 < 0.1f || yc0 > 0.9f) ? 1.f : 0.f;
            const float v1 = (xc1 < 0.1f || xc1 > 0.9f || yc1 < 0.1f || yc1 > 0.9f) ? 1.f : 0.f;
            w[3] += 50.f * 0.5f * (v0 + v1);
        }
#pragma unroll
        for (int c = 0; c < 5; ++c)
            w[c] = fminf(fmaxf(w[c], 0.1f), 10.f);
    }
    float wsumc[5];
#pragma unroll
    for (int c = 0; c < 5; ++c) wsumc[c] = wred_sum(w[c]);

    if (lane == 0) {
        float dist[5], cw[5], s = 0.f;
#pragma unroll
        for (int c = 0; c < 5; ++c) {
            dist[c] = sm[11 + c];
            cw[c] = 1.f / (sqrtf(dist[c]) + 1e-7f);
            s += cw[c];
        }
        float wf[5], wsum = 0.f, W = 0.f, nllnum = 0.f, Ssum = 0.f;
#pragma unroll
        for (int c = 0; c < 5; ++c) {
            cw[c] = cw[c] / s * 5.f;
            wf[c] = (wsumc[c] / 32.f) * cw[c];
            wsum += wf[c] * dist[c];
            W += wf[c];
            nllnum += wf[c] * sm[5 + c];
            Ssum += wf[c] * sm[c];
        }
        const float nll = nllnum / wsum;
        const float smooth = (W * sm[10] - Ssum) / wsum;
        out[0] = 0.8f * nll + 0.04f * smooth;
    }
}

extern "C" void kernel_launch(void* const* d_in, const int* in_sizes, int n_in,
                              void* d_out, int out_size, void* d_ws, size_t ws_size,
                              hipStream_t stream) {
    const float* outputs = (const float*)d_in[0];
    const int*   labels  = (const int*)d_in[1];
    const float* points  = (const float*)d_in[2];
    float* out = (float*)d_out;

    int bpb = 16;  // 512 blocks total: 8 waves/CU in main, 72 KB partials
    while (bpb > 4 &&
           (size_t)(27 + 9) * 4 * BATCH * (size_t)bpb > ws_size)
        bpb >>= 1;
    const int nblk = BATCH * bpb;
    const int iters = NPTS / (bpb * 1024);

    float* pf = (float*)d_ws;
    unsigned int* pi = (unsigned int*)(pf + (size_t)27 * nblk);

    bsl_main<<<nblk, 256, 0, stream>>>(outputs, labels, points, pf, pi, bpb, iters);
    bsl_reduce_final<<<1, 1024, 0, stream>>>(pf, pi, bpb, out);
}